// Round 7
// baseline (184.675 us; speedup 1.0000x reference)
//
#include <hip/hip_runtime.h>
#include <hip/hip_bf16.h>

// ---------------------------------------------------------------------------
// LocalAttention: out = (softmax_mask(QK^T*s) V) Wo + bo, sliding causal W=256
// S=4096, D=1024, H=16, hd=64. bf16 MFMA (16x16x32), f32 accum.
// R7: BARRIER-FREE pipelined GEMM. Each wave double-buffers its own private
//     A-half/B-half in LDS (no cross-wave deps -> zero __syncthreads), issues
//     tile k+1's global_load_lds before computing tile k, and gates compute
//     on manual s_waitcnt vmcnt(NLOADS) so prefetch stays in flight (the
//     AITER-style pipeline the 2-barrier K-loop cannot express).
// Evidence log: R2 44.2 (BK32,16KB) < R6 50.5 (BK64,32KB,0 conflicts) <
//     R5 59.7 -> barrier *count* and conflicts are NOT the levers; the
//     vmcnt(0)-at-barrier drain scales with staged bytes (wash). Hence:
//     remove the barriers, not tune them.
// ---------------------------------------------------------------------------

typedef __attribute__((ext_vector_type(8))) short bf16x8;
typedef __attribute__((ext_vector_type(4))) float f32x4;

#define S_LEN 4096
#define D_MODEL 1024
#define N_HEADS 16
#define HEAD_DIM 64
#define WINDOW 256
#define QKV_LD 3072

static __device__ __forceinline__ unsigned short f2bfbits(float f) {
    __hip_bfloat16 h = __float2bfloat16(f);
    unsigned short u;
    __builtin_memcpy(&u, &h, sizeof(u));
    return u;
}

typedef const __attribute__((address_space(1))) void c_gvoid;
typedef __attribute__((address_space(3))) void lvoid;
static __device__ __forceinline__ void gload16(const void* g, void* l) {
    __builtin_amdgcn_global_load_lds((c_gvoid*)g, (lvoid*)l, 16, 0, 0);
}

// ---------------- fused prep: x-cast, W transposes, bias concat -------------
__global__ __launch_bounds__(256) void prep_k(const float* __restrict__ x,
                                              const float* __restrict__ Wq,
                                              const float* __restrict__ Wk,
                                              const float* __restrict__ Wv,
                                              const float* __restrict__ Wo,
                                              const float* __restrict__ bq,
                                              const float* __restrict__ bk,
                                              const float* __restrict__ bv,
                                              unsigned short* __restrict__ xb,
                                              __hip_bfloat16* __restrict__ Wqkvt,
                                              __hip_bfloat16* __restrict__ Wot,
                                              float* __restrict__ bias_cat) {
    const int b = blockIdx.x;
    const int t = threadIdx.x;
    if (b < 2048) {
        int i = b * 2048 + t * 8;
        float4 v0 = *(const float4*)(x + i);
        float4 v1 = *(const float4*)(x + i + 4);
        ushort4 o0, o1;
        o0.x = f2bfbits(v0.x); o0.y = f2bfbits(v0.y);
        o0.z = f2bfbits(v0.z); o0.w = f2bfbits(v0.w);
        o1.x = f2bfbits(v1.x); o1.y = f2bfbits(v1.y);
        o1.z = f2bfbits(v1.z); o1.w = f2bfbits(v1.w);
        *(ushort4*)(xb + i) = o0;
        *(ushort4*)(xb + i + 4) = o1;
        return;
    }
    if (b < 3072) {
        __shared__ __hip_bfloat16 tile[64][65];
        const int m = (b - 2048) >> 8;
        const int tid = (b - 2048) & 255;
        const int n0 = (tid & 15) * 64, k0 = (tid >> 4) * 64;
        const float* src = (m == 0) ? Wq : (m == 1) ? Wk : (m == 2) ? Wv : Wo;
        __hip_bfloat16* dst = (m < 3) ? (Wqkvt + (size_t)m * D_MODEL * D_MODEL) : Wot;
        for (int c = t; c < 1024; c += 256) {
            int r = c >> 4, c4 = (c & 15) * 4;
            float4 v = *(const float4*)(src + (size_t)(k0 + r) * D_MODEL + n0 + c4);
            tile[r][c4 + 0] = __float2bfloat16(v.x);
            tile[r][c4 + 1] = __float2bfloat16(v.y);
            tile[r][c4 + 2] = __float2bfloat16(v.z);
            tile[r][c4 + 3] = __float2bfloat16(v.w);
        }
        __syncthreads();
        for (int c = t; c < 1024; c += 256) {
            int rr = c >> 4, c4 = (c & 15) * 4;
            ushort4 o;
            unsigned short u0, u1, u2, u3;
            __builtin_memcpy(&u0, &tile[c4 + 0][rr], 2);
            __builtin_memcpy(&u1, &tile[c4 + 1][rr], 2);
            __builtin_memcpy(&u2, &tile[c4 + 2][rr], 2);
            __builtin_memcpy(&u3, &tile[c4 + 3][rr], 2);
            o.x = u0; o.y = u1; o.z = u2; o.w = u3;
            *(ushort4*)((unsigned short*)dst + (size_t)(n0 + rr) * D_MODEL + k0 + c4) = o;
        }
        return;
    }
    for (int c = t; c < 3 * D_MODEL; c += 256) {
        float v = (c < 1024) ? bq[c] : (c < 2048) ? bk[c - 1024] : bv[c - 2048];
        bias_cat[c] = v;
    }
}

// ---------------- barrier-free pipelined GEMM -------------------------------
// C[M][N] = A[M][K](bf16) * Bt[N][K](bf16)^T + bias. BK=32.
// Wave w owns C sub-tile [wm:wm+TM/2) x [wn:wn+TN/2) and stages ITS OWN
// A rows [wm,wm+TM/2) and B rows [wn,wn+TN/2) into private double-buffered
// LDS. No __syncthreads anywhere. Pipeline: issue gloads for tile k+1, then
// s_waitcnt vmcnt(NLOADS) (waits only tile k's loads), ds_read, MFMA.
// Waves sharing the same A/B half are in the same block -> L1 absorbs the
// duplicate staging.
template <int TM, int TN, bool OUT_BF16>
__global__ __launch_bounds__(256) void gemm_bias_k(const __hip_bfloat16* __restrict__ A,
                                                   const __hip_bfloat16* __restrict__ Bt,
                                                   const float* __restrict__ bias,
                                                   void* __restrict__ Cout,
                                                   int M, int N, int K) {
    constexpr int MI = TM / 32;            // frags along M per wave (half = MI*16 rows)
    constexpr int NI = TN / 32;
    constexpr int AH = (TM / 2) * 32;      // elems per A half-tile buffer
    constexpr int BH = (TN / 2) * 32;
    constexpr int NLOADS = TM / 32 + TN / 32;   // gloads per stage (1KB each)
    // s_waitcnt imm: exp=7, lgkm=15 (don't care), vmcnt = N (N<16)
    constexpr int WAIT_PREV = 0xF70 | NLOADS;
    constexpr int WAIT_ALL  = 0xF70;

    __shared__ __align__(16) __hip_bfloat16 lds[4 * 2 * (AH + BH)];

    const int m0 = blockIdx.y * TM, n0 = blockIdx.x * TN;
    const int t = threadIdx.x;
    const int wave = t >> 6, lane = t & 63;
    const int quad = lane >> 4, l16 = lane & 15;
    const int wm = (wave & 1) * (TM / 2), wn = (wave >> 1) * (TN / 2);

    __hip_bfloat16* wbase = lds + wave * 2 * (AH + BH);

    // staging coords: one gload covers 16 rows x 32 cols (64 lanes x 16B)
    const int srow = lane >> 2;        // 0..15
    const int scol = (lane & 3) * 8;   // 0,8,16,24

    f32x4 acc[MI][NI];
#pragma unroll
    for (int mi = 0; mi < MI; ++mi)
#pragma unroll
        for (int ni = 0; ni < NI; ++ni) acc[mi][ni] = (f32x4){0.f, 0.f, 0.f, 0.f};

    const __hip_bfloat16* gA = A + (size_t)(m0 + wm + srow) * K + scol;
    const __hip_bfloat16* gB = Bt + (size_t)(n0 + wn + srow) * K + scol;

    const int ITERS = K / 32;

    // prologue: stage tile 0 into buf 0
    {
        __hip_bfloat16* d = wbase;
#pragma unroll
        for (int p = 0; p < TM / 32; ++p)
            gload16(gA + (size_t)(p * 16) * K, d + p * 512 + lane * 8);
        d += AH;
#pragma unroll
        for (int p = 0; p < TN / 32; ++p)
            gload16(gB + (size_t)(p * 16) * K, d + p * 512 + lane * 8);
    }

    for (int it = 0; it < ITERS; ++it) {
        if (it + 1 < ITERS) {
            // prefetch tile it+1 into the other buffer
            __hip_bfloat16* d = wbase + ((it + 1) & 1) * (AH + BH);
            const int k0 = (it + 1) * 32;
#pragma unroll
            for (int p = 0; p < TM / 32; ++p)
                gload16(gA + (size_t)(p * 16) * K + k0, d + p * 512 + lane * 8);
            d += AH;
#pragma unroll
            for (int p = 0; p < TN / 32; ++p)
                gload16(gB + (size_t)(p * 16) * K + k0, d + p * 512 + lane * 8);
            __builtin_amdgcn_s_waitcnt(WAIT_PREV);   // tile `it` loads done
        } else {
            __builtin_amdgcn_s_waitcnt(WAIT_ALL);
        }

        const __hip_bfloat16* ab = wbase + (it & 1) * (AH + BH);
        const __hip_bfloat16* bb = ab + AH;
        bf16x8 af[MI], bfr[NI];
#pragma unroll
        for (int mi = 0; mi < MI; ++mi)
            af[mi] = *(const bf16x8*)&ab[(mi * 16 + l16) * 32 + quad * 8];
#pragma unroll
        for (int ni = 0; ni < NI; ++ni)
            bfr[ni] = *(const bf16x8*)&bb[(ni * 16 + l16) * 32 + quad * 8];
#pragma unroll
        for (int mi = 0; mi < MI; ++mi)
#pragma unroll
            for (int ni = 0; ni < NI; ++ni)
                acc[mi][ni] = __builtin_amdgcn_mfma_f32_16x16x32_bf16(
                    bfr[ni], af[mi], acc[mi][ni], 0, 0, 0);
    }

    // epilogue: rows m = wm+mi*16+l16; cols n = wn+ni*16+quad*4 + (0..3)
    float4 bv[NI];
#pragma unroll
    for (int ni = 0; ni < NI; ++ni)
        bv[ni] = *(const float4*)&bias[n0 + wn + ni * 16 + quad * 4];
#pragma unroll
    for (int mi = 0; mi < MI; ++mi) {
        const int row = m0 + wm + mi * 16 + l16;
#pragma unroll
        for (int ni = 0; ni < NI; ++ni) {
            const int col = n0 + wn + ni * 16 + quad * 4;
            if (OUT_BF16) {
                ushort4 o;
                o.x = f2bfbits(acc[mi][ni][0] + bv[ni].x);
                o.y = f2bfbits(acc[mi][ni][1] + bv[ni].y);
                o.z = f2bfbits(acc[mi][ni][2] + bv[ni].z);
                o.w = f2bfbits(acc[mi][ni][3] + bv[ni].w);
                *(ushort4*)((unsigned short*)Cout + (size_t)row * N + col) = o;
            } else {
                float4 o;
                o.x = acc[mi][ni][0] + bv[ni].x;
                o.y = acc[mi][ni][1] + bv[ni].y;
                o.z = acc[mi][ni][2] + bv[ni].z;
                o.w = acc[mi][ni][3] + bv[ni].w;
                *(float4*)((float*)Cout + (size_t)row * N + col) = o;
            }
        }
    }
}

// ---------------- sliding-window flash attention (swapped layout) -----------
__global__ __launch_bounds__(256) void attn_k(const __hip_bfloat16* __restrict__ QKV,
                                              __hip_bfloat16* __restrict__ AO) {
    __shared__ __align__(16) __hip_bfloat16 Qs[64 * 64];
    __shared__ __align__(16) __hip_bfloat16 Ks[64 * 64];
    __shared__ __align__(16) __hip_bfloat16 Vt[64 * 72];  // [hd][key], padded
    __shared__ __align__(16) __hip_bfloat16 Ps[64 * 72];  // [q][key], padded

    const int h = blockIdx.y;
    const int i0 = blockIdx.x * 64;
    const int t = threadIdx.x;
    const int wave = t >> 6, lane = t & 63;
    const int quad = lane >> 4, l16 = lane & 15;
    const float sc = 0.125f * 1.44269504088896f;  // 1/sqrt(64) * log2(e)

    const __hip_bfloat16* Q = QKV + h * HEAD_DIM;
    const __hip_bfloat16* K = QKV + D_MODEL + h * HEAD_DIM;
    const __hip_bfloat16* V = QKV + 2 * D_MODEL + h * HEAD_DIM;

    const int grow = t >> 3;                       // 0..31
    const int glog = ((t & 7) ^ ((t >> 3) & 7)) * 8;
#pragma unroll
    for (int p = 0; p < 2; ++p)
        gload16(Q + (size_t)(i0 + p * 32 + grow) * QKV_LD + glog,
                &Qs[p * 2048 + t * 8]);
    __syncthreads();

    const int rq = wave * 16 + l16;   // this lane's q row (block-relative)
    const int qi = i0 + rq;           // absolute q index
    bf16x8 aq[2];
#pragma unroll
    for (int kk = 0; kk < 2; ++kk)
        aq[kk] = *(const bf16x8*)&Qs[rq * 64 + ((kk * 4 + quad) ^ (rq & 7)) * 8];

    float m_i = -3.0e38f, l_i = 0.f;
    f32x4 Ov[4];
#pragma unroll
    for (int no = 0; no < 4; ++no) Ov[no] = (f32x4){0.f, 0.f, 0.f, 0.f};

    const int vp = t >> 3, vc = t & 7;

    for (int tt = 0; tt < 5; ++tt) {
        const int tb = i0 - WINDOW + tt * 64;
        if (tb < 0) continue;  // uniform across block

#pragma unroll
        for (int p = 0; p < 2; ++p)
            gload16(K + (size_t)(tb + p * 32 + grow) * QKV_LD + glog,
                    &Ks[p * 2048 + t * 8]);
        {
            uint4 v0 = *(const uint4*)(V + (size_t)(tb + 2 * vp) * QKV_LD + vc * 8);
            uint4 v1 = *(const uint4*)(V + (size_t)(tb + 2 * vp + 1) * QKV_LD + vc * 8);
            const unsigned short* a0 = (const unsigned short*)&v0;
            const unsigned short* a1 = (const unsigned short*)&v1;
#pragma unroll
            for (int j = 0; j < 8; ++j) {
                unsigned int pk = (unsigned int)a0[j] | ((unsigned int)a1[j] << 16);
                *(unsigned int*)&Vt[(vc * 8 + j) * 72 + 2 * vp] = pk;
            }
        }
        __syncthreads();

        // S' = K Q^T (swapped): lane holds keys ni*16+quad*4+(0..3) for q=qi
        f32x4 s[4];
#pragma unroll
        for (int ni = 0; ni < 4; ++ni) s[ni] = (f32x4){0.f, 0.f, 0.f, 0.f};
#pragma unroll
        for (int kk = 0; kk < 2; ++kk)
#pragma unroll
            for (int ni = 0; ni < 4; ++ni) {
                int rk = ni * 16 + l16;
                bf16x8 bk = *(const bf16x8*)&Ks[rk * 64 + ((kk * 4 + quad) ^ (rk & 7)) * 8];
                s[ni] = __builtin_amdgcn_mfma_f32_16x16x32_bf16(bk, aq[kk], s[ni], 0, 0, 0);
            }

        // mask + online softmax (lane-scalar state)
        float p[4][4], mx = -3.0e38f;
#pragma unroll
        for (int ni = 0; ni < 4; ++ni)
#pragma unroll
            for (int r = 0; r < 4; ++r) {
                int j = tb + ni * 16 + quad * 4 + r;
                float v = s[ni][r] * sc;
                bool ok = (j <= qi) && (qi - j < WINDOW);
                v = ok ? v : -3.0e38f;
                p[ni][r] = v;
                mx = fmaxf(mx, v);
            }
        mx = fmaxf(mx, __shfl_xor(mx, 16));
        mx = fmaxf(mx, __shfl_xor(mx, 32));
        const float mn = fmaxf(m_i, mx);
        const float alpha = exp2f(m_i - mn);
        m_i = mn;
        float sum = 0.f;
#pragma unroll
        for (int ni = 0; ni < 4; ++ni)
#pragma unroll
            for (int r = 0; r < 4; ++r) {
                float e = exp2f(p[ni][r] - mn);
                p[ni][r] = e;
                sum += e;
            }
        sum += __shfl_xor(sum, 16);
        sum += __shfl_xor(sum, 32);
        l_i = l_i * alpha + sum;
#pragma unroll
        for (int no = 0; no < 4; ++no) Ov[no] *= alpha;

        // P' -> Ps in A-layout: row = q (rq), cols = 4 consecutive keys
#pragma unroll
        for (int ni = 0; ni < 4; ++ni) {
            ushort4 w4;
            w4.x = f2bfbits(p[ni][0]); w4.y = f2bfbits(p[ni][1]);
            w4.z = f2bfbits(p[ni][2]); w4.w = f2bfbits(p[ni][3]);
            *(ushort4*)&Ps[rq * 72 + ni * 16 + quad * 4] = w4;
        }

        // O' += V^T P^T (swapped): lane gets hd = no*16+quad*4+(0..3), q = qi
#pragma unroll
        for (int kk = 0; kk < 2; ++kk) {
            bf16x8 ap = *(const bf16x8*)&Ps[rq * 72 + kk * 32 + quad * 8];
#pragma unroll
            for (int no = 0; no < 4; ++no) {
                bf16x8 bvv = *(const bf16x8*)&Vt[(no * 16 + l16) * 72 + kk * 32 + quad * 8];
                Ov[no] = __builtin_amdgcn_mfma_f32_16x16x32_bf16(bvv, ap, Ov[no], 0, 0, 0);
            }
        }
        __syncthreads();  // protect Ks/Vt before next tile's staging
    }

    const float inv = 1.0f / l_i;
#pragma unroll
    for (int no = 0; no < 4; ++no) {
        ushort4 o;
        o.x = f2bfbits(Ov[no][0] * inv);
        o.y = f2bfbits(Ov[no][1] * inv);
        o.z = f2bfbits(Ov[no][2] * inv);
        o.w = f2bfbits(Ov[no][3] * inv);
        *(ushort4*)((unsigned short*)AO + (size_t)qi * D_MODEL + h * HEAD_DIM +
                    no * 16 + quad * 4) = o;
    }
}

// ---------------------------------------------------------------------------
extern "C" void kernel_launch(void* const* d_in, const int* in_sizes, int n_in,
                              void* d_out, int out_size, void* d_ws, size_t ws_size,
                              hipStream_t stream) {
    const float* x  = (const float*)d_in[0];
    const float* Wq = (const float*)d_in[1];
    const float* Wk = (const float*)d_in[2];
    const float* Wv = (const float*)d_in[3];
    const float* Wo = (const float*)d_in[4];
    const float* bq = (const float*)d_in[5];
    const float* bk = (const float*)d_in[6];
    const float* bv = (const float*)d_in[7];
    const float* bo = (const float*)d_in[8];
    float* out = (float*)d_out;

    char* w = (char*)d_ws;
    const size_t MB = 1u << 20;
    __hip_bfloat16* xb    = (__hip_bfloat16*)(w + 0 * MB);   // 8 MB
    __hip_bfloat16* Wqkvt = (__hip_bfloat16*)(w + 8 * MB);   // 6 MB [3072][1024]
    __hip_bfloat16* Wot   = (__hip_bfloat16*)(w + 14 * MB);  // 2 MB
    float*          bcat  = (float*)(w + 16 * MB);           // 12 KB
    __hip_bfloat16* QKV   = (__hip_bfloat16*)(w + 17 * MB);  // 24 MB [4096][3072]
    __hip_bfloat16* AO    = (__hip_bfloat16*)(w + 41 * MB);  // 8 MB, end 49 MB

    prep_k<<<3073, 256, 0, stream>>>(x, Wq, Wk, Wv, Wo, bq, bk, bv,
                                     (unsigned short*)xb, Wqkvt, Wot, bcat);

    // fused QKV projection: 128x128 tiles, grid (24, 32) = 768 blocks
    dim3 gqkv(QKV_LD / 128, S_LEN / 128);
    gemm_bias_k<128, 128, true><<<gqkv, 256, 0, stream>>>(
        xb, Wqkvt, bcat, QKV, S_LEN, QKV_LD, D_MODEL);

    dim3 ag(S_LEN / 64, N_HEADS);
    attn_k<<<ag, 256, 0, stream>>>(QKV, AO);

    // output projection: 128x64 tiles, grid (16, 32) = 512 blocks
    dim3 go(D_MODEL / 64, S_LEN / 128);
    gemm_bias_k<128, 64, false><<<go, 256, 0, stream>>>(
        AO, Wot, bo, out, S_LEN, D_MODEL, D_MODEL);
}

// Round 8
// 182.116 us; speedup vs baseline: 1.0141x; 1.0141x over previous
//
#include <hip/hip_runtime.h>
#include <hip/hip_bf16.h>

// ---------------------------------------------------------------------------
// LocalAttention: out = (softmax_mask(QK^T*s) V) Wo + bo, sliding causal W=256
// S=4096, D=1024, H=16, hd=64. bf16 MFMA (16x16x32), f32 accum.
// R8: GEMM = R2's proven core (128x128, BK=32, 16KB LDS; every structural
//     variant R3/R5/R6/R7 lost to it) + swapped-operand vectorized epilogue.
//     Attention: 128-query blocks -> 6 k-tiles per 128q (vs 10), 40% less
//     MFMA+staging per query, half the barriers; 2 q-rows per lane.
// Evidence log: BK64/0-conflict (R6 50.5), wave-private zero-barrier (R7
//     52.5), 64x128 tile (R5 59.7), XCD pin (R3 57.4) ALL lose to R2 44.2;
//     K=1024 plateau of the 2-barrier structure. Non-QKV remainder ~130us
//     every round -> attn/Wo are the pot.
// ---------------------------------------------------------------------------

typedef __attribute__((ext_vector_type(8))) short bf16x8;
typedef __attribute__((ext_vector_type(4))) float f32x4;

#define S_LEN 4096
#define D_MODEL 1024
#define N_HEADS 16
#define HEAD_DIM 64
#define WINDOW 256
#define QKV_LD 3072

static __device__ __forceinline__ unsigned short f2bfbits(float f) {
    __hip_bfloat16 h = __float2bfloat16(f);
    unsigned short u;
    __builtin_memcpy(&u, &h, sizeof(u));
    return u;
}

typedef const __attribute__((address_space(1))) void c_gvoid;
typedef __attribute__((address_space(3))) void lvoid;
static __device__ __forceinline__ void gload16(const void* g, void* l) {
    __builtin_amdgcn_global_load_lds((c_gvoid*)g, (lvoid*)l, 16, 0, 0);
}

// ---------------- fused prep: x-cast, W transposes, bias concat -------------
__global__ __launch_bounds__(256) void prep_k(const float* __restrict__ x,
                                              const float* __restrict__ Wq,
                                              const float* __restrict__ Wk,
                                              const float* __restrict__ Wv,
                                              const float* __restrict__ Wo,
                                              const float* __restrict__ bq,
                                              const float* __restrict__ bk,
                                              const float* __restrict__ bv,
                                              unsigned short* __restrict__ xb,
                                              __hip_bfloat16* __restrict__ Wqkvt,
                                              __hip_bfloat16* __restrict__ Wot,
                                              float* __restrict__ bias_cat) {
    const int b = blockIdx.x;
    const int t = threadIdx.x;
    if (b < 2048) {
        int i = b * 2048 + t * 8;
        float4 v0 = *(const float4*)(x + i);
        float4 v1 = *(const float4*)(x + i + 4);
        ushort4 o0, o1;
        o0.x = f2bfbits(v0.x); o0.y = f2bfbits(v0.y);
        o0.z = f2bfbits(v0.z); o0.w = f2bfbits(v0.w);
        o1.x = f2bfbits(v1.x); o1.y = f2bfbits(v1.y);
        o1.z = f2bfbits(v1.z); o1.w = f2bfbits(v1.w);
        *(ushort4*)(xb + i) = o0;
        *(ushort4*)(xb + i + 4) = o1;
        return;
    }
    if (b < 3072) {
        __shared__ __hip_bfloat16 tile[64][65];
        const int m = (b - 2048) >> 8;
        const int tid = (b - 2048) & 255;
        const int n0 = (tid & 15) * 64, k0 = (tid >> 4) * 64;
        const float* src = (m == 0) ? Wq : (m == 1) ? Wk : (m == 2) ? Wv : Wo;
        __hip_bfloat16* dst = (m < 3) ? (Wqkvt + (size_t)m * D_MODEL * D_MODEL) : Wot;
        for (int c = t; c < 1024; c += 256) {
            int r = c >> 4, c4 = (c & 15) * 4;
            float4 v = *(const float4*)(src + (size_t)(k0 + r) * D_MODEL + n0 + c4);
            tile[r][c4 + 0] = __float2bfloat16(v.x);
            tile[r][c4 + 1] = __float2bfloat16(v.y);
            tile[r][c4 + 2] = __float2bfloat16(v.z);
            tile[r][c4 + 3] = __float2bfloat16(v.w);
        }
        __syncthreads();
        for (int c = t; c < 1024; c += 256) {
            int rr = c >> 4, c4 = (c & 15) * 4;
            ushort4 o;
            unsigned short u0, u1, u2, u3;
            __builtin_memcpy(&u0, &tile[c4 + 0][rr], 2);
            __builtin_memcpy(&u1, &tile[c4 + 1][rr], 2);
            __builtin_memcpy(&u2, &tile[c4 + 2][rr], 2);
            __builtin_memcpy(&u3, &tile[c4 + 3][rr], 2);
            o.x = u0; o.y = u1; o.z = u2; o.w = u3;
            *(ushort4*)((unsigned short*)dst + (size_t)(n0 + rr) * D_MODEL + k0 + c4) = o;
        }
        return;
    }
    for (int c = t; c < 3 * D_MODEL; c += 256) {
        float v = (c < 1024) ? bq[c] : (c < 2048) ? bk[c - 1024] : bv[c - 2048];
        bias_cat[c] = v;
    }
}

// ---------------- GEMM: C[M][N] = A[M][K] * Bt[N][K]^T + bias ---------------
// R2's core: BK=32, unpadded 64B LDS rows, gload16 staging, 2-barrier K-loop.
// Only change vs R2: swapped MFMA operands -> lane's 4 acc elems are 4
// consecutive N-cols -> ushort4/float4 C stores + float4 bias.
template <int TM, int TN, bool OUT_BF16>
__global__ __launch_bounds__(256) void gemm_bias_k(const __hip_bfloat16* __restrict__ A,
                                                   const __hip_bfloat16* __restrict__ Bt,
                                                   const float* __restrict__ bias,
                                                   void* __restrict__ Cout,
                                                   int M, int N, int K) {
    constexpr int MI = TM / 32;   // wave covers TM/2 rows -> MI 16-row frags
    constexpr int NI = TN / 32;
    __shared__ __align__(16) __hip_bfloat16 As[TM * 32];
    __shared__ __align__(16) __hip_bfloat16 Bs[TN * 32];

    const int m0 = blockIdx.y * TM, n0 = blockIdx.x * TN;
    const int t = threadIdx.x;
    const int wave = t >> 6, lane = t & 63;
    const int quad = lane >> 4, l16 = lane & 15;
    const int wm = (wave & 1) * (TM / 2), wn = (wave >> 1) * (TN / 2);

    // staging: one pass = 64 rows x 4 chunks of 16B (2048 elems = t*8)
    const int srow = t >> 2;           // 0..63
    const int scol = (t & 3) * 8;      // 0,8,16,24

    f32x4 acc[MI][NI];
#pragma unroll
    for (int mi = 0; mi < MI; ++mi)
#pragma unroll
        for (int ni = 0; ni < NI; ++ni) acc[mi][ni] = (f32x4){0.f, 0.f, 0.f, 0.f};

    const __hip_bfloat16* gA = A + (size_t)(m0 + srow) * K + scol;
    const __hip_bfloat16* gB = Bt + (size_t)(n0 + srow) * K + scol;

    for (int k0 = 0; k0 < K; k0 += 32) {
#pragma unroll
        for (int p = 0; p < TM / 64; ++p)
            gload16(gA + (size_t)(p * 64) * K + k0, &As[p * 2048 + t * 8]);
#pragma unroll
        for (int p = 0; p < TN / 64; ++p)
            gload16(gB + (size_t)(p * 64) * K + k0, &Bs[p * 2048 + t * 8]);
        __syncthreads();

        bf16x8 af[MI], bfr[NI];
#pragma unroll
        for (int mi = 0; mi < MI; ++mi)
            af[mi] = *(const bf16x8*)&As[(wm + mi * 16 + l16) * 32 + quad * 8];
#pragma unroll
        for (int ni = 0; ni < NI; ++ni)
            bfr[ni] = *(const bf16x8*)&Bs[(wn + ni * 16 + l16) * 32 + quad * 8];
#pragma unroll
        for (int mi = 0; mi < MI; ++mi)
#pragma unroll
            for (int ni = 0; ni < NI; ++ni)
                acc[mi][ni] = __builtin_amdgcn_mfma_f32_16x16x32_bf16(
                    bfr[ni], af[mi], acc[mi][ni], 0, 0, 0);
        __syncthreads();
    }

    // epilogue: rows m = wm+mi*16+l16; cols n = wn+ni*16+quad*4 + (0..3)
    float4 bv[NI];
#pragma unroll
    for (int ni = 0; ni < NI; ++ni)
        bv[ni] = *(const float4*)&bias[n0 + wn + ni * 16 + quad * 4];
#pragma unroll
    for (int mi = 0; mi < MI; ++mi) {
        const int row = m0 + wm + mi * 16 + l16;
#pragma unroll
        for (int ni = 0; ni < NI; ++ni) {
            const int col = n0 + wn + ni * 16 + quad * 4;
            if (OUT_BF16) {
                ushort4 o;
                o.x = f2bfbits(acc[mi][ni][0] + bv[ni].x);
                o.y = f2bfbits(acc[mi][ni][1] + bv[ni].y);
                o.z = f2bfbits(acc[mi][ni][2] + bv[ni].z);
                o.w = f2bfbits(acc[mi][ni][3] + bv[ni].w);
                *(ushort4*)((unsigned short*)Cout + (size_t)row * N + col) = o;
            } else {
                float4 o;
                o.x = acc[mi][ni][0] + bv[ni].x;
                o.y = acc[mi][ni][1] + bv[ni].y;
                o.z = acc[mi][ni][2] + bv[ni].z;
                o.w = acc[mi][ni][3] + bv[ni].w;
                *(float4*)((float*)Cout + (size_t)row * N + col) = o;
            }
        }
    }
}

// ---------------- sliding-window flash attention, 128-q blocks --------------
// block: 1 head x 128 q (4 waves x 32 q; lane owns q rows rq0=w*32+l16 and
// rq0+16). 6 key tiles of 64 cover [i0-256, i0+128) -> 40% less staging+MFMA
// per query and half the barriers vs 64-q blocks. Swapped MFMAs: softmax
// m/l/alpha are 2 lane scalars; P & O stores are ushort4. Fully-masked early
// tiles self-correct: alpha=exp2(-3e38-m_real)=0 wipes their contribution.
__global__ __launch_bounds__(256) void attn_k(const __hip_bfloat16* __restrict__ QKV,
                                              __hip_bfloat16* __restrict__ AO) {
    __shared__ __align__(16) __hip_bfloat16 Qs[128 * 64];   // 16 KB, XOR-8 rows
    __shared__ __align__(16) __hip_bfloat16 Ks[64 * 64];    // 8 KB, XOR-8 rows
    __shared__ __align__(16) __hip_bfloat16 Vt[64 * 72];    // [hd][key], padded
    __shared__ __align__(16) __hip_bfloat16 Ps[128 * 72];   // [q][key], padded

    const int h = blockIdx.y;
    const int i0 = blockIdx.x * 128;
    const int t = threadIdx.x;
    const int wave = t >> 6, lane = t & 63;
    const int quad = lane >> 4, l16 = lane & 15;
    const float sc = 0.125f * 1.44269504088896f;  // 1/sqrt(64) * log2(e)

    const __hip_bfloat16* Q = QKV + h * HEAD_DIM;
    const __hip_bfloat16* K = QKV + D_MODEL + h * HEAD_DIM;
    const __hip_bfloat16* V = QKV + 2 * D_MODEL + h * HEAD_DIM;

    // stage Q via gload: 4 passes of 32 rows x 64 cols (XOR-8 swizzle)
    const int grow = t >> 3;                       // 0..31
    const int glog = ((t & 7) ^ ((t >> 3) & 7)) * 8;
#pragma unroll
    for (int p = 0; p < 4; ++p)
        gload16(Q + (size_t)(i0 + p * 32 + grow) * QKV_LD + glog,
                &Qs[p * 2048 + t * 8]);
    __syncthreads();

    const int rq0 = wave * 32 + l16;     // lane's two q rows: rq0, rq0+16
    bf16x8 aq[2][2];
#pragma unroll
    for (int m = 0; m < 2; ++m) {
        const int rq = rq0 + m * 16;
#pragma unroll
        for (int kk = 0; kk < 2; ++kk)
            aq[m][kk] = *(const bf16x8*)&Qs[rq * 64 + ((kk * 4 + quad) ^ (rq & 7)) * 8];
    }

    float m_i[2] = {-3.0e38f, -3.0e38f}, l_i[2] = {0.f, 0.f};
    f32x4 Ov[2][4];
#pragma unroll
    for (int m = 0; m < 2; ++m)
#pragma unroll
        for (int no = 0; no < 4; ++no) Ov[m][no] = (f32x4){0.f, 0.f, 0.f, 0.f};

    const int vp = t >> 3, vc = t & 7;

    for (int tt = 0; tt < 6; ++tt) {
        const int tb = i0 - WINDOW + tt * 64;
        if (tb < 0) continue;  // uniform across block

        // stage K via gload (2 passes of 32 rows)
#pragma unroll
        for (int p = 0; p < 2; ++p)
            gload16(K + (size_t)(tb + p * 32 + grow) * QKV_LD + glog,
                    &Ks[p * 2048 + t * 8]);
        // stage V transposed (2 rows packed per b32 write)
        {
            uint4 v0 = *(const uint4*)(V + (size_t)(tb + 2 * vp) * QKV_LD + vc * 8);
            uint4 v1 = *(const uint4*)(V + (size_t)(tb + 2 * vp + 1) * QKV_LD + vc * 8);
            const unsigned short* a0 = (const unsigned short*)&v0;
            const unsigned short* a1 = (const unsigned short*)&v1;
#pragma unroll
            for (int j = 0; j < 8; ++j) {
                unsigned int pk = (unsigned int)a0[j] | ((unsigned int)a1[j] << 16);
                *(unsigned int*)&Vt[(vc * 8 + j) * 72 + 2 * vp] = pk;
            }
        }
        __syncthreads();

        // S' = K Q^T (swapped): lane holds keys ni*16+quad*4+(0..3), q = qi[m]
        f32x4 s[2][4];
#pragma unroll
        for (int m = 0; m < 2; ++m)
#pragma unroll
            for (int ni = 0; ni < 4; ++ni) s[m][ni] = (f32x4){0.f, 0.f, 0.f, 0.f};
#pragma unroll
        for (int kk = 0; kk < 2; ++kk)
#pragma unroll
            for (int ni = 0; ni < 4; ++ni) {
                int rk = ni * 16 + l16;
                bf16x8 bk = *(const bf16x8*)&Ks[rk * 64 + ((kk * 4 + quad) ^ (rk & 7)) * 8];
#pragma unroll
                for (int m = 0; m < 2; ++m)
                    s[m][ni] = __builtin_amdgcn_mfma_f32_16x16x32_bf16(
                        bk, aq[m][kk], s[m][ni], 0, 0, 0);
            }

#pragma unroll
        for (int m = 0; m < 2; ++m) {
            const int qi = i0 + rq0 + m * 16;
            // mask + online softmax (lane-scalar state)
            float mx = -3.0e38f;
#pragma unroll
            for (int ni = 0; ni < 4; ++ni)
#pragma unroll
                for (int r = 0; r < 4; ++r) {
                    int j = tb + ni * 16 + quad * 4 + r;
                    float v = s[m][ni][r] * sc;
                    bool ok = (j <= qi) && (qi - j < WINDOW);
                    v = ok ? v : -3.0e38f;
                    s[m][ni][r] = v;
                    mx = fmaxf(mx, v);
                }
            mx = fmaxf(mx, __shfl_xor(mx, 16));
            mx = fmaxf(mx, __shfl_xor(mx, 32));
            const float mn = fmaxf(m_i[m], mx);
            const float alpha = exp2f(m_i[m] - mn);
            m_i[m] = mn;
            float sum = 0.f;
#pragma unroll
            for (int ni = 0; ni < 4; ++ni)
#pragma unroll
                for (int r = 0; r < 4; ++r) {
                    float e = exp2f(s[m][ni][r] - mn);
                    s[m][ni][r] = e;
                    sum += e;
                }
            sum += __shfl_xor(sum, 16);
            sum += __shfl_xor(sum, 32);
            l_i[m] = l_i[m] * alpha + sum;
#pragma unroll
            for (int no = 0; no < 4; ++no) Ov[m][no] *= alpha;

            // P' -> Ps in A-layout: row = q, cols = 4 consecutive keys
            const int rq = rq0 + m * 16;
#pragma unroll
            for (int ni = 0; ni < 4; ++ni) {
                ushort4 w4;
                w4.x = f2bfbits(s[m][ni][0]); w4.y = f2bfbits(s[m][ni][1]);
                w4.z = f2bfbits(s[m][ni][2]); w4.w = f2bfbits(s[m][ni][3]);
                *(ushort4*)&Ps[rq * 72 + ni * 16 + quad * 4] = w4;
            }
        }

        // O' += V^T P^T (swapped): lane gets hd = no*16+quad*4+(0..3)
#pragma unroll
        for (int kk = 0; kk < 2; ++kk) {
            bf16x8 ap[2];
#pragma unroll
            for (int m = 0; m < 2; ++m)
                ap[m] = *(const bf16x8*)&Ps[(rq0 + m * 16) * 72 + kk * 32 + quad * 8];
#pragma unroll
            for (int no = 0; no < 4; ++no) {
                bf16x8 bvv = *(const bf16x8*)&Vt[(no * 16 + l16) * 72 + kk * 32 + quad * 8];
#pragma unroll
                for (int m = 0; m < 2; ++m)
                    Ov[m][no] = __builtin_amdgcn_mfma_f32_16x16x32_bf16(
                        bvv, ap[m], Ov[m][no], 0, 0, 0);
            }
        }
        __syncthreads();  // protect Ks/Vt before next tile's staging
    }

    // normalize + vectorized store (4 consecutive hd per reg group)
#pragma unroll
    for (int m = 0; m < 2; ++m) {
        const float inv = 1.0f / l_i[m];
        const int qi = i0 + rq0 + m * 16;
#pragma unroll
        for (int no = 0; no < 4; ++no) {
            ushort4 o;
            o.x = f2bfbits(Ov[m][no][0] * inv);
            o.y = f2bfbits(Ov[m][no][1] * inv);
            o.z = f2bfbits(Ov[m][no][2] * inv);
            o.w = f2bfbits(Ov[m][no][3] * inv);
            *(ushort4*)((unsigned short*)AO + (size_t)qi * D_MODEL + h * HEAD_DIM +
                        no * 16 + quad * 4) = o;
        }
    }
}

// ---------------------------------------------------------------------------
extern "C" void kernel_launch(void* const* d_in, const int* in_sizes, int n_in,
                              void* d_out, int out_size, void* d_ws, size_t ws_size,
                              hipStream_t stream) {
    const float* x  = (const float*)d_in[0];
    const float* Wq = (const float*)d_in[1];
    const float* Wk = (const float*)d_in[2];
    const float* Wv = (const float*)d_in[3];
    const float* Wo = (const float*)d_in[4];
    const float* bq = (const float*)d_in[5];
    const float* bk = (const float*)d_in[6];
    const float* bv = (const float*)d_in[7];
    const float* bo = (const float*)d_in[8];
    float* out = (float*)d_out;

    char* w = (char*)d_ws;
    const size_t MB = 1u << 20;
    __hip_bfloat16* xb    = (__hip_bfloat16*)(w + 0 * MB);   // 8 MB
    __hip_bfloat16* Wqkvt = (__hip_bfloat16*)(w + 8 * MB);   // 6 MB [3072][1024]
    __hip_bfloat16* Wot   = (__hip_bfloat16*)(w + 14 * MB);  // 2 MB
    float*          bcat  = (float*)(w + 16 * MB);           // 12 KB
    __hip_bfloat16* QKV   = (__hip_bfloat16*)(w + 17 * MB);  // 24 MB [4096][3072]
    __hip_bfloat16* AO    = (__hip_bfloat16*)(w + 41 * MB);  // 8 MB, end 49 MB

    prep_k<<<3073, 256, 0, stream>>>(x, Wq, Wk, Wv, Wo, bq, bk, bv,
                                     (unsigned short*)xb, Wqkvt, Wot, bcat);

    // fused QKV projection: 128x128 tiles, grid (24, 32) = 768 blocks
    dim3 gqkv(QKV_LD / 128, S_LEN / 128);
    gemm_bias_k<128, 128, true><<<gqkv, 256, 0, stream>>>(
        xb, Wqkvt, bcat, QKV, S_LEN, QKV_LD, D_MODEL);

    // attention: 128-q blocks, grid (32, 16) = 512 blocks
    dim3 ag(S_LEN / 128, N_HEADS);
    attn_k<<<ag, 256, 0, stream>>>(QKV, AO);

    // output projection: 128x64 tiles, grid (16, 32) = 512 blocks
    dim3 go(D_MODEL / 64, S_LEN / 128);
    gemm_bias_k<128, 64, false><<<go, 256, 0, stream>>>(
        AO, Wot, bo, out, S_LEN, D_MODEL, D_MODEL);
}